// Round 8
// baseline (89.398 us; speedup 1.0000x reference)
//
#include <hip/hip_runtime.h>

#define NP   320                // particles
#define HD   32                 // hidden dim
#define MT   4                  // trajectories
#define LS   6                  // snapshots
#define BB   (MT * (LS - 1))    // 20 batch elements
#define NCFG (MT * LS)          // 24 configs
#define ROWS (NCFG * NP)        // 7680 rows
#define RPB  8                  // rows (waves) per block
#define BT   (64 * RPB)         // 512 threads
#define GRID (ROWS / RPB)       // 960 blocks
#define SIG2 0.01f
#define L2E2 2.8853900817779268f  // 2*log2(e)

#define NCELL 512
#define RMAX  12.0f
#define TSCALE ((float)NCELL / RMAX)
#define CWID   (RMAX / (float)NCELL)

// ws layout (floats)
#define OFF_S0  0
#define OFF_S1  ROWS

__device__ __forceinline__ float fexp2(float x){ return __builtin_amdgcn_exp2f(x); }
__device__ __forceinline__ float frcp(float x){ return __builtin_amdgcn_rcpf(x); }
__device__ __forceinline__ float frsq(float x){ return __builtin_amdgcn_rsqf(x); }

// --------------------------------------------------------------------------
// One WAVE per row (cfg, i); RPB rows/block (RPB | 320 -> single-config
// blocks). Each block BUILDS its own radial table in LDS (1 cell/thread,
// 32 tanh each — cheaper than a separate dispatch + global staging), stages
// positions, then: per pair one rsq + two b128 lerp gathers; in-wave shfl
// reductions; closed-form one-body V on lanes 0..31; per-row stores.
//
// tanh(z) = 1-2rc, rc = 1/(exp2(L2E2*z)+1); (1-t^2) = 4(rc-rc^2)
// table: (Phi'(r), Phi''(r), phi~(r)=sum_h w2[h] tanh(r w+b), 0)
// --------------------------------------------------------------------------
__global__ __launch_bounds__(BT) void main_kernel(
    const float* __restrict__ data,      // (MT, LS, NP, 2)
    const float* __restrict__ t_snap,    // (LS,)
    const float* __restrict__ V_w1,      // (2, HD)
    const float* __restrict__ V_b1,      // (HD,)
    const float* __restrict__ V_w2,      // (HD,)
    const float* __restrict__ V_b2,      // (1,)
    const float* __restrict__ Phi_w1,    // (HD,)
    const float* __restrict__ Phi_b1,    // (HD,)
    const float* __restrict__ Phi_w2,    // (HD,)
    const float* __restrict__ Phi_b2,    // (1,)
    float* __restrict__ ws)
{
    __shared__ float4 sTab[NCELL + 1];
    __shared__ float2 sX[NP];

    const int tid  = threadIdx.x;
    const int lane = tid & 63;
    const int wid  = tid >> 6;
    const int row0 = blockIdx.x * RPB;
    const int cfg  = row0 / NP;
    const int l    = cfg % LS;

    // ---- build radial table in-block (uniform h -> scalar weight loads) ----
    for (int c = tid; c < NCELL + 1; c += BT) {
        float rr = (float)c * CWID;
        float f1 = 0.0f, f2 = 0.0f, f3 = 0.0f;
        #pragma unroll
        for (int h = 0; h < HD; ++h) {
            float w  = Phi_w1[h];
            float bb = Phi_b1[h];
            float w2 = Phi_w2[h];
            float e  = fexp2(fmaf(rr, w, bb) * L2E2);
            float rc = frcp(e + 1.0f);
            float u  = fmaf(-rc, rc, rc);        // (1-t^2)/4
            float t  = fmaf(-2.0f, rc, 1.0f);    // tanh
            f1 = fmaf(u,     4.0f * w * w2,      f1);   // Phi'
            f2 = fmaf(u * t, -8.0f * w * w * w2, f2);   // Phi''
            f3 = fmaf(t, w2, f3);                       // phi~
        }
        sTab[c] = make_float4(f1, f2, f3, 0.0f);
    }
    // ---- stage positions ----
    {
        const float2* Xg = (const float2*)(data + (size_t)cfg * NP * 2);
        for (int c = tid; c < NP; c += BT) sX[c] = Xg[c];
    }
    __syncthreads();

    const int i = row0 - cfg * NP + wid;
    const float2 xi = sX[i];

    float gx = 0.0f, gy = 0.0f, lp = 0.0f, ph = 0.0f;
    #pragma unroll
    for (int k = 0; k < NP / 64; ++k) {
        const int j = lane + 64 * k;
        const float2 xj = sX[j];
        const float d0 = xi.x - xj.x;
        const float d1 = xi.y - xj.y;
        const float sq = fmaf(d1, d1, d0 * d0);
        const float inv = frsq(sq);              // 1/r; inf on diagonal
        const float r   = sq * inv;              // NaN on diagonal
        float x = fminf(r * TSCALE, (float)NCELL - 0.001f);  // NaN-safe clamp
        const int   i0 = (int)x;
        const float fr = x - (float)i0;
        const float4 a = sTab[i0];
        const float4 b = sTab[i0 + 1];
        const float f1 = fmaf(b.x - a.x, fr, a.x);   // Phi'(r)
        const float f2 = fmaf(b.y - a.y, fr, a.y);   // Phi''(r)
        const float f3 = fmaf(b.z - a.z, fr, a.z);   // phi~(r)
        const float t0 = f1 * inv;                   // Phi'/r
        float cgx = t0 * d0;
        float cgy = t0 * d1;
        float clp = f2 + t0;                         // Phi'' + (d-1)/r*Phi'
        float cph = f3;
        if (j == i) { cgx = 0.0f; cgy = 0.0f; clp = 0.0f; cph = 0.0f; }
        gx += cgx; gy += cgy; lp += clp; ph += cph;
    }
    #pragma unroll
    for (int off = 32; off; off >>= 1) {
        gx += __shfl_down(gx, off, 64);
        gy += __shfl_down(gy, off, 64);
        lp += __shfl_down(lp, off, 64);
        ph += __shfl_down(ph, off, 64);
    }

    // one-body V terms, lanes 0..31 (h = lane)
    float gvx = 0.0f, gvy = 0.0f, lv = 0.0f, vv = 0.0f;
    if (lane < HD) {
        float w0 = V_w1[lane];
        float w1 = V_w1[HD + lane];
        float z  = fmaf(xi.x, w0, fmaf(xi.y, w1, V_b1[lane]));
        float e  = fexp2(z * L2E2);
        float rc = frcp(e + 1.0f);
        float u  = fmaf(-rc, rc, rc);
        float t  = fmaf(-2.0f, rc, 1.0f);
        float v2 = V_w2[lane];
        float cu = 4.0f * u * v2;
        gvx = cu * w0;
        gvy = cu * w1;
        lv  = -8.0f * u * t * v2 * (w0 * w0 + w1 * w1);
        vv  = t * v2;
        #pragma unroll
        for (int off = 16; off; off >>= 1) {
            gvx += __shfl_xor(gvx, off, 64);
            gvy += __shfl_xor(gvy, off, 64);
            lv  += __shfl_xor(lv,  off, 64);
            vv  += __shfl_xor(vv,  off, 64);
        }
    }

    if (lane == 0) {
        const float invN = 1.0f / (float)NP;
        float c0 = 0.0f, c1 = 0.0f;
        if (l < LS - 1) {
            float dx = -gvx - gx * invN;
            float dy = -gvy - gy * invN;
            float lap_sum = lv + lp * invN;
            float dt = t_snap[l + 1] - t_snap[l];
            c0 = dt * (dx * dx + dy * dy) * invN + SIG2 * dt * lap_sum * invN;
        }
        if (l == 0 || l == LS - 1) {
            const float coef = (l == LS - 1) ? 1.0f : -1.0f;
            float v = vv + V_b2[0];
            float P = ph + (float)(NP - 1) * Phi_b2[0];
            c1 = coef * (v * invN + P * invN * invN);
        }
        const int row = row0 + wid;
        ws[OFF_S0 + row] = c0;
        ws[OFF_S1 + row] = c1;
    }
}

// --------------------------------------------------------------------------
// Reduce: out = ((sum S0 - 2*sum S1)/BB)^2
// --------------------------------------------------------------------------
__global__ __launch_bounds__(1024) void reduce_kernel(
    const float* __restrict__ ws, float* __restrict__ out)
{
    __shared__ float sR[16][2];
    const int tid = threadIdx.x;
    float a0 = 0.0f, a1 = 0.0f;
    for (int idx = tid; idx < ROWS; idx += 1024) {
        a0 += ws[OFF_S0 + idx];
        a1 += ws[OFF_S1 + idx];
    }
    #pragma unroll
    for (int off = 32; off; off >>= 1) {
        a0 += __shfl_down(a0, off, 64);
        a1 += __shfl_down(a1, off, 64);
    }
    const int lane = tid & 63, wid = tid >> 6;
    if (lane == 0) { sR[wid][0] = a0; sR[wid][1] = a1; }
    __syncthreads();
    if (tid == 0) {
        float S0 = 0.0f, S1 = 0.0f;
        #pragma unroll
        for (int w = 0; w < 16; ++w) { S0 += sR[w][0]; S1 += sR[w][1]; }
        float res = (S0 - 2.0f * S1) / (float)BB;
        out[0] = res * res;
    }
}

extern "C" void kernel_launch(void* const* d_in, const int* in_sizes, int n_in,
                              void* d_out, int out_size, void* d_ws, size_t ws_size,
                              hipStream_t stream) {
    const float* data    = (const float*)d_in[0];
    const float* t_snap  = (const float*)d_in[1];
    const float* V_w1    = (const float*)d_in[2];
    const float* V_b1    = (const float*)d_in[3];
    const float* V_w2    = (const float*)d_in[4];
    const float* V_b2    = (const float*)d_in[5];
    const float* Phi_w1  = (const float*)d_in[6];
    const float* Phi_b1  = (const float*)d_in[7];
    const float* Phi_w2  = (const float*)d_in[8];
    const float* Phi_b2  = (const float*)d_in[9];
    float* ws  = (float*)d_ws;
    float* out = (float*)d_out;

    main_kernel<<<GRID, BT, 0, stream>>>(
        data, t_snap, V_w1, V_b1, V_w2, V_b2, Phi_w1, Phi_b1, Phi_w2, Phi_b2, ws);

    reduce_kernel<<<1, 1024, 0, stream>>>(ws, out);
}

// Round 9
// 84.671 us; speedup vs baseline: 1.0558x; 1.0558x over previous
//
#include <hip/hip_runtime.h>

#define NP   320                // particles
#define HD   32                 // hidden dim
#define MT   4                  // trajectories
#define LS   6                  // snapshots
#define BB   (MT * (LS - 1))    // 20 batch elements
#define NCFG (MT * LS)          // 24 configs
#define ROWS (NCFG * NP)        // 7680 rows
#define RPB  8                  // rows (waves) per block
#define BT   (64 * RPB)         // 512 threads
#define GRID (ROWS / RPB)       // 960 blocks
#define SIG2 0.01f
#define L2E2 2.8853900817779268f  // 2*log2(e)

#define NCELL 512
#define RMAX  12.0f
#define TSCALE ((float)NCELL / RMAX)
#define CWID   (RMAX / (float)NCELL)

// ws layout (floats)
#define OFF_TAB 0               // float4[NCELL+1] = 2052 floats (pad to 2112)
#define OFF_S0  2112            // float[GRID]
#define OFF_S1  (2112 + GRID)   // float[GRID]

__device__ __forceinline__ float fexp2(float x){ return __builtin_amdgcn_exp2f(x); }
__device__ __forceinline__ float frcp(float x){ return __builtin_amdgcn_rcpf(x); }
__device__ __forceinline__ float frsq(float x){ return __builtin_amdgcn_rsqf(x); }

// --------------------------------------------------------------------------
// Build radial table once (1 block, 512 threads, ~1 cell/thread):
//   cell c -> r = c*CWID: (Phi'(r), Phi''(r), phi~(r)=sum_h w2[h] tanh(rw+b), 0)
// tanh(z) = 1-2rc, rc = 1/(exp2(L2E2*z)+1); (1-t^2) = 4(rc-rc^2)
// --------------------------------------------------------------------------
__global__ __launch_bounds__(512) void build_table_kernel(
    const float* __restrict__ Phi_w1, const float* __restrict__ Phi_b1,
    const float* __restrict__ Phi_w2, float* __restrict__ ws)
{
    float4* tab = (float4*)(ws + OFF_TAB);
    for (int c = threadIdx.x; c < NCELL + 1; c += 512) {
        float rr = (float)c * CWID;
        float f1 = 0.0f, f2 = 0.0f, f3 = 0.0f;
        #pragma unroll
        for (int h = 0; h < HD; ++h) {
            float w  = Phi_w1[h];
            float bb = Phi_b1[h];
            float w2 = Phi_w2[h];
            float e  = fexp2(fmaf(rr, w, bb) * L2E2);
            float rc = frcp(e + 1.0f);
            float u  = fmaf(-rc, rc, rc);        // (1-t^2)/4
            float t  = fmaf(-2.0f, rc, 1.0f);    // tanh
            f1 = fmaf(u,     4.0f * w * w2,      f1);   // Phi'
            f2 = fmaf(u * t, -8.0f * w * w * w2, f2);   // Phi''
            f3 = fmaf(t, w2, f3);                       // phi~
        }
        tab[c] = make_float4(f1, f2, f3, 0.0f);
    }
}

// --------------------------------------------------------------------------
// One WAVE per row (cfg, i); RPB rows/block (single-config blocks).
// Stage table + positions to LDS; per pair one rsq + two b128 lerp gathers;
// in-wave shfl reductions; closed-form one-body V (weights hoisted above the
// pair loop to hide load latency). Block pre-reduces its 8 rows' partials
// -> 2 floats per block (no atomics, no fences).
// --------------------------------------------------------------------------
__global__ __launch_bounds__(BT) void main_kernel(
    const float* __restrict__ data,      // (MT, LS, NP, 2)
    const float* __restrict__ t_snap,    // (LS,)
    const float* __restrict__ V_w1,      // (2, HD)
    const float* __restrict__ V_b1,      // (HD,)
    const float* __restrict__ V_w2,      // (HD,)
    const float* __restrict__ V_b2,      // (1,)
    const float* __restrict__ Phi_b2,    // (1,)
    float* __restrict__ ws)
{
    __shared__ float4 sTab[NCELL + 1];
    __shared__ float2 sX[NP];
    __shared__ float  sRed[RPB][2];

    const int tid  = threadIdx.x;
    const int lane = tid & 63;
    const int wid  = tid >> 6;
    const int row0 = blockIdx.x * RPB;
    const int cfg  = row0 / NP;
    const int l    = cfg % LS;

    // ---- hoisted one-body weight loads (consumed after the pair loop) ----
    const int hh = lane & (HD - 1);
    const float vw0 = V_w1[hh];
    const float vw1 = V_w1[HD + hh];
    const float vb1 = V_b1[hh];
    const float vw2 = V_w2[hh];

    // ---- stage table + positions ----
    {
        const float4* gT = (const float4*)(ws + OFF_TAB);
        const float2* Xg = (const float2*)(data + (size_t)cfg * NP * 2);
        for (int c = tid; c < NCELL + 1; c += BT) sTab[c] = gT[c];
        for (int c = tid; c < NP; c += BT) sX[c] = Xg[c];
    }
    __syncthreads();

    const int i = row0 - cfg * NP + wid;
    const float2 xi = sX[i];

    float gx = 0.0f, gy = 0.0f, lp = 0.0f, ph = 0.0f;
    #pragma unroll
    for (int k = 0; k < NP / 64; ++k) {
        const int j = lane + 64 * k;
        const float2 xj = sX[j];
        const float d0 = xi.x - xj.x;
        const float d1 = xi.y - xj.y;
        const float sq = fmaf(d1, d1, d0 * d0);
        const float inv = frsq(sq);              // 1/r; inf on diagonal
        const float r   = sq * inv;              // NaN on diagonal
        float x = fminf(r * TSCALE, (float)NCELL - 0.001f);  // NaN-safe clamp
        const int   i0 = (int)x;
        const float fr = x - (float)i0;
        const float4 a = sTab[i0];
        const float4 b = sTab[i0 + 1];
        const float f1 = fmaf(b.x - a.x, fr, a.x);   // Phi'(r)
        const float f2 = fmaf(b.y - a.y, fr, a.y);   // Phi''(r)
        const float f3 = fmaf(b.z - a.z, fr, a.z);   // phi~(r)
        const float t0 = f1 * inv;                   // Phi'/r
        float cgx = t0 * d0;
        float cgy = t0 * d1;
        float clp = f2 + t0;                         // Phi'' + (d-1)/r*Phi'
        float cph = f3;
        if (j == i) { cgx = 0.0f; cgy = 0.0f; clp = 0.0f; cph = 0.0f; }
        gx += cgx; gy += cgy; lp += clp; ph += cph;
    }
    #pragma unroll
    for (int off = 32; off; off >>= 1) {
        gx += __shfl_down(gx, off, 64);
        gy += __shfl_down(gy, off, 64);
        lp += __shfl_down(lp, off, 64);
        ph += __shfl_down(ph, off, 64);
    }

    // ---- one-body V terms (h = lane&31; halves duplicate, lane 0 read) ----
    float gvx, gvy, lv, vv;
    {
        float z  = fmaf(xi.x, vw0, fmaf(xi.y, vw1, vb1));
        float e  = fexp2(z * L2E2);
        float rc = frcp(e + 1.0f);
        float u  = fmaf(-rc, rc, rc);
        float t  = fmaf(-2.0f, rc, 1.0f);
        float cu = 4.0f * u * vw2;
        gvx = cu * vw0;
        gvy = cu * vw1;
        lv  = -8.0f * u * t * vw2 * (vw0 * vw0 + vw1 * vw1);
        vv  = t * vw2;
        #pragma unroll
        for (int off = 16; off; off >>= 1) {
            gvx += __shfl_xor(gvx, off, 64);
            gvy += __shfl_xor(gvy, off, 64);
            lv  += __shfl_xor(lv,  off, 64);
            vv  += __shfl_xor(vv,  off, 64);
        }
    }

    if (lane == 0) {
        const float invN = 1.0f / (float)NP;
        float c0 = 0.0f, c1 = 0.0f;
        if (l < LS - 1) {
            float dx = -gvx - gx * invN;
            float dy = -gvy - gy * invN;
            float lap_sum = lv + lp * invN;
            float dt = t_snap[l + 1] - t_snap[l];
            c0 = dt * (dx * dx + dy * dy) * invN + SIG2 * dt * lap_sum * invN;
        }
        if (l == 0 || l == LS - 1) {
            const float coef = (l == LS - 1) ? 1.0f : -1.0f;
            float v = vv + V_b2[0];
            float P = ph + (float)(NP - 1) * Phi_b2[0];
            c1 = coef * (v * invN + P * invN * invN);
        }
        sRed[wid][0] = c0;
        sRed[wid][1] = c1;
    }
    __syncthreads();

    if (tid == 0) {
        float S0 = 0.0f, S1 = 0.0f;
        #pragma unroll
        for (int w = 0; w < RPB; ++w) { S0 += sRed[w][0]; S1 += sRed[w][1]; }
        ws[OFF_S0 + blockIdx.x] = S0;
        ws[OFF_S1 + blockIdx.x] = S1;
    }
}

// --------------------------------------------------------------------------
// Reduce 960+960 block partials: out = ((sum S0 - 2*sum S1)/BB)^2
// --------------------------------------------------------------------------
__global__ __launch_bounds__(256) void reduce_kernel(
    const float* __restrict__ ws, float* __restrict__ out)
{
    __shared__ float sR[4][2];
    const int tid = threadIdx.x;
    float a0 = 0.0f, a1 = 0.0f;
    #pragma unroll
    for (int k = 0; k < 4; ++k) {
        int idx = tid + 256 * k;
        if (idx < GRID) {
            a0 += ws[OFF_S0 + idx];
            a1 += ws[OFF_S1 + idx];
        }
    }
    #pragma unroll
    for (int off = 32; off; off >>= 1) {
        a0 += __shfl_down(a0, off, 64);
        a1 += __shfl_down(a1, off, 64);
    }
    const int lane = tid & 63, wid = tid >> 6;
    if (lane == 0) { sR[wid][0] = a0; sR[wid][1] = a1; }
    __syncthreads();
    if (tid == 0) {
        float S0 = sR[0][0] + sR[1][0] + sR[2][0] + sR[3][0];
        float S1 = sR[0][1] + sR[1][1] + sR[2][1] + sR[3][1];
        float res = (S0 - 2.0f * S1) / (float)BB;
        out[0] = res * res;
    }
}

extern "C" void kernel_launch(void* const* d_in, const int* in_sizes, int n_in,
                              void* d_out, int out_size, void* d_ws, size_t ws_size,
                              hipStream_t stream) {
    const float* data    = (const float*)d_in[0];
    const float* t_snap  = (const float*)d_in[1];
    const float* V_w1    = (const float*)d_in[2];
    const float* V_b1    = (const float*)d_in[3];
    const float* V_w2    = (const float*)d_in[4];
    const float* V_b2    = (const float*)d_in[5];
    const float* Phi_w1  = (const float*)d_in[6];
    const float* Phi_b1  = (const float*)d_in[7];
    const float* Phi_w2  = (const float*)d_in[8];
    const float* Phi_b2  = (const float*)d_in[9];
    float* ws  = (float*)d_ws;
    float* out = (float*)d_out;

    build_table_kernel<<<1, 512, 0, stream>>>(Phi_w1, Phi_b1, Phi_w2, ws);

    main_kernel<<<GRID, BT, 0, stream>>>(
        data, t_snap, V_w1, V_b1, V_w2, V_b2, Phi_b2, ws);

    reduce_kernel<<<1, 256, 0, stream>>>(ws, out);
}